// Round 4
// baseline (83603.656 us; speedup 1.0000x reference)
//
#include <hip/hip_runtime.h>
#include <hip/hip_bf16.h>

#define BB 256
#define TT 2000
#define FF 42
#define NTHREADS 640

__device__ __forceinline__ float bf2f(__hip_bfloat16 v) { return __bfloat162float(v); }
__device__ __forceinline__ float sig(float x) { return 1.0f / (1.0f + __expf(-x)); }
__device__ __forceinline__ float tanh_fast(float x) {
    float e = __expf(2.0f * x);
    return 1.0f - 2.0f / (e + 1.0f);
}
__device__ __forceinline__ float unpk_lo(unsigned u) {
    union { unsigned u; float f; } c; c.u = u << 16; return c.f;
}
__device__ __forceinline__ float unpk_hi(unsigned u) {
    union { unsigned u; float f; } c; c.u = u & 0xffff0000u; return c.f;
}
// fp32 -> bf16 bits, round-to-nearest-even
__device__ __forceinline__ unsigned f2bfbits(float f) {
    union { float f; unsigned u; } c; c.f = f;
    unsigned r = c.u + 0x7FFFu + ((c.u >> 16) & 1u);
    return r >> 16;
}
__device__ __forceinline__ unsigned pack2(float a, float b) {
    return f2bfbits(a) | (f2bfbits(b) << 16);
}
__device__ __forceinline__ float gld(const void* p, int i, bool f32) {
    return f32 ? ((const float*)p)[i] : bf2f(((const __hip_bfloat16*)p)[i]);
}

// Per-thread weight arrays. CRITICAL SIZE CONSTRAINT (rounds 0-3 A/B):
// a 57-dword local array is register-promoted; a 94-dword one is sent to
// scratch (57 GB HBM traffic, 8x slowdown) regardless of launch_bounds or
// indexing form. Keep every aggregate <= 58 dwords.
#define NWA 58
#define NWB 46

// packed bf16 weights (register array, compile-time offset OFF) · fp32 input
// (LDS float4 broadcast), 4 acc chains. Array-ref + constant indices only.
template<int OFF, int NF4, int N>
__device__ __forceinline__ float dot4(const unsigned (&w)[N], const float4* in, float acc) {
    float a0 = acc, a1 = 0.f, a2 = 0.f, a3 = 0.f;
    #pragma unroll
    for (int i = 0; i < NF4; ++i) {
        float4 d = in[i];
        unsigned u0 = w[OFF + 2 * i], u1 = w[OFF + 2 * i + 1];
        a0 = fmaf(unpk_lo(u0), d.x, a0);
        a1 = fmaf(unpk_hi(u0), d.y, a1);
        a2 = fmaf(unpk_lo(u1), d.z, a2);
        a3 = fmaf(unpk_hi(u1), d.w, a3);
    }
    return (a0 + a1) + (a2 + a3);
}

__global__ __launch_bounds__(NTHREADS, 1)
void rnn_fused(const void* __restrict__ x,
               const void* __restrict__ dense_w, const void* __restrict__ dense_b,
               const void* __restrict__ vad_w_ih, const void* __restrict__ vad_w_hh,
               const void* __restrict__ vad_b_ih, const void* __restrict__ vad_b_hh,
               const void* __restrict__ vad_out_w, const void* __restrict__ vad_out_b,
               const void* __restrict__ noise_w_ih, const void* __restrict__ noise_w_hh,
               const void* __restrict__ noise_b_ih, const void* __restrict__ noise_b_hh,
               const void* __restrict__ den_w_ih, const void* __restrict__ den_w_hh,
               const void* __restrict__ den_b_ih, const void* __restrict__ den_b_hh,
               const void* __restrict__ out_w, const void* __restrict__ out_b,
               void* __restrict__ d_out) {
    // ---- LDS (~6 KiB): only activations/state/partials; weights live in VGPRs ----
    __shared__ __align__(16) float sXT[44];    // x(t) fp32 (+pad zeros)
    __shared__ __align__(16) float sTMP[24];   // dense out
    __shared__ __align__(16) float sHV[24];    // h_vad
    __shared__ __align__(16) float sHN[48];    // h_noise
    __shared__ __align__(16) float sHD[96];    // h_den
    __shared__ __align__(16) float sHR[96];    // relu(h_den)
    __shared__ __align__(16) float sNIN[92];   // [tmp | vad | x] (+pad)
    __shared__ __align__(16) float sDIN[116];  // [vad | relu(noise) | x] (+pad)
    __shared__ float sNPI[144], sNPH[144];     // noise partials
    __shared__ float sGI[288], sGH[288];       // den partials
    __shared__ int sBad;

    const int tid = threadIdx.x;
    const int b = blockIdx.x;
    const int nt = NTHREADS;

    // ---- dtype detection (validated in earlier rounds) ----
    if (tid == 0) sBad = 0;
    __syncthreads();
    {
        const unsigned* w = (const unsigned*)dense_w;
        for (int i = tid; i < 500; i += nt) {
            float av = fabsf(unpk_lo(w[i]));
            if (!(av <= 1e3f)) { atomicAdd(&sBad, 1); break; }
        }
    }
    __syncthreads();
    const bool F32 = (sBad > 0);

    const float* xbf = (const float*)x + (size_t)b * TT * FF;
    const __hip_bfloat16* xbh = (const __hip_bfloat16*)x + (size_t)b * TT * FF;
    float* odf = (float*)d_out;
    __hip_bfloat16* odh = (__hip_bfloat16*)d_out;
    float* ovf = odf + (size_t)BB * TT * 22;
    __hip_bfloat16* ovh = odh + (size_t)BB * TT * 22;

    // ---- role-partitioned weight registers (two small arrays, see NWA note) ----
    // tid   0-287: wA[0..56] = den_w_ih row tid (+wA[57]=0 pad)
    // tid  96-119:   + wB[0..20] = dense row (tid-96) (+wB[21]=0 pad)
    // tid 288-311: wA[0..35] = vad ih gates r,z,n (12w each); wB[0..35] = vad hh gates
    // tid     312: wA[0..11] = vad_out row
    // tid 320-607: wA[0..47] = den_w_hh row (tid-320)
    // tid 320-463:   + wB[0..44] = noise_w_ih row (tid-320) (+wB[45]=0 pad)
    // tid 464-607:   + wB[0..23] = noise_w_hh row (tid-464)
    // tid 608-629: wA[0..47] = out_w row (tid-608)
    unsigned wA[NWA], wB[NWB];
    #pragma unroll
    for (int i = 0; i < NWA; ++i) wA[i] = 0u;
    #pragma unroll
    for (int i = 0; i < NWB; ++i) wB[i] = 0u;
    float b_main = 0.f, b_aux = 0.f;
    float bv0 = 0.f, bv1 = 0.f, bv2 = 0.f, bv3 = 0.f, bv4 = 0.f, bv5 = 0.f;
    float hvreg = 0.f;

    if (tid < 288) {
        #pragma unroll
        for (int i = 0; i < 57; ++i)
            wA[i] = pack2(gld(den_w_ih, tid * 114 + 2 * i, F32),
                          gld(den_w_ih, tid * 114 + 2 * i + 1, F32));
        b_main = gld(den_b_ih, tid, F32);
        if (tid >= 96 && tid < 120) {
            int o = tid - 96;
            #pragma unroll
            for (int i = 0; i < 21; ++i)
                wB[i] = pack2(gld(dense_w, o * 42 + 2 * i, F32),
                              gld(dense_w, o * 42 + 2 * i + 1, F32));
            b_aux = gld(dense_b, o, F32);
        }
    } else if (tid < 312) {
        int o = tid - 288;
        #pragma unroll
        for (int g = 0; g < 3; ++g) {
            #pragma unroll
            for (int i = 0; i < 12; ++i) {
                wA[g * 12 + i] = pack2(gld(vad_w_ih, (g * 24 + o) * 24 + 2 * i, F32),
                                       gld(vad_w_ih, (g * 24 + o) * 24 + 2 * i + 1, F32));
                wB[g * 12 + i] = pack2(gld(vad_w_hh, (g * 24 + o) * 24 + 2 * i, F32),
                                       gld(vad_w_hh, (g * 24 + o) * 24 + 2 * i + 1, F32));
            }
        }
        bv0 = gld(vad_b_ih, o, F32);      bv1 = gld(vad_b_ih, 24 + o, F32);
        bv2 = gld(vad_b_ih, 48 + o, F32); bv3 = gld(vad_b_hh, o, F32);
        bv4 = gld(vad_b_hh, 24 + o, F32); bv5 = gld(vad_b_hh, 48 + o, F32);
    } else if (tid == 312) {
        #pragma unroll
        for (int i = 0; i < 12; ++i)
            wA[i] = pack2(gld(vad_out_w, 2 * i, F32), gld(vad_out_w, 2 * i + 1, F32));
        b_main = gld(vad_out_b, 0, F32);
    } else if (tid >= 320 && tid < 608) {
        int o = tid - 320;
        #pragma unroll
        for (int i = 0; i < 48; ++i)
            wA[i] = pack2(gld(den_w_hh, o * 96 + 2 * i, F32),
                          gld(den_w_hh, o * 96 + 2 * i + 1, F32));
        b_main = gld(den_b_hh, o, F32);
        if (o < 144) {
            #pragma unroll
            for (int i = 0; i < 45; ++i)
                wB[i] = pack2(gld(noise_w_ih, o * 90 + 2 * i, F32),
                              gld(noise_w_ih, o * 90 + 2 * i + 1, F32));
            b_aux = gld(noise_b_ih, o, F32);
        } else {
            int o2 = o - 144;
            #pragma unroll
            for (int i = 0; i < 24; ++i)
                wB[i] = pack2(gld(noise_w_hh, o2 * 48 + 2 * i, F32),
                              gld(noise_w_hh, o2 * 48 + 2 * i + 1, F32));
            b_aux = gld(noise_b_hh, o2, F32);
        }
    } else if (tid >= 608 && tid < 630) {
        int o = tid - 608;
        #pragma unroll
        for (int i = 0; i < 48; ++i)
            wA[i] = pack2(gld(out_w, o * 96 + 2 * i, F32),
                          gld(out_w, o * 96 + 2 * i + 1, F32));
        b_main = gld(out_b, o, F32);
    }

    // ---- prologue: zero state, stage x(0), prefetch x(1) ----
    for (int i = tid; i < 24; i += nt) { sHV[i] = 0.f; sTMP[i] = 0.f; }
    for (int i = tid; i < 48; i += nt) sHN[i] = 0.f;
    for (int i = tid; i < 96; i += nt) { sHD[i] = 0.f; sHR[i] = 0.f; }
    if (tid < 2) { sXT[42 + tid] = 0.f; sNIN[90 + tid] = 0.f; sDIN[114 + tid] = 0.f; }
    if (tid < FF) {
        float v = F32 ? xbf[tid] : bf2f(xbh[tid]);
        sXT[tid] = v; sNIN[48 + tid] = v; sDIN[72 + tid] = v;
    }
    float xreg = 0.f;
    if (tid >= 464 && tid < 464 + FF) {
        int j = tid - 464;
        xreg = F32 ? xbf[FF + j] : bf2f(xbh[FF + j]);
    }
    __syncthreads();
    // dense(0)
    if (tid >= 96 && tid < 120) {
        int o = tid - 96;
        float v = tanh_fast(dot4<0, 11>(wB, (const float4*)sXT, b_aux));
        sTMP[o] = v; sNIN[o] = v;
    }
    __syncthreads();

    for (int t = 0; t < TT; ++t) {
        // ---- S2: den hh [waves 5-9] || vad fused GRU [wave 4] || out head(t-1) [wave 9 hi] ----
        if (tid >= 320 && tid < 608) {
            sGH[tid - 320] = dot4<0, 24>(wA, (const float4*)sHD, b_main);
        } else if (tid >= 288 && tid < 312) {
            // all 24 vad threads are in wave 4: lockstep read-then-write of sHV is safe
            int o = tid - 288;
            const float4* tmp4 = (const float4*)sTMP;
            const float4* hv4 = (const float4*)sHV;
            float xr = dot4<0,  6>(wA, tmp4, bv0);
            float xz = dot4<12, 6>(wA, tmp4, bv1);
            float xn = dot4<24, 6>(wA, tmp4, bv2);
            float hr = dot4<0,  6>(wB, hv4, bv3);
            float hz = dot4<12, 6>(wB, hv4, bv4);
            float hn = dot4<24, 6>(wB, hv4, bv5);
            float r = sig(xr + hr);
            float z = sig(xz + hz);
            float n = tanh_fast(xn + r * hn);
            float h = (1.f - z) * n + z * hvreg;
            hvreg = h;
            sHV[o] = h; sNIN[24 + o] = h; sDIN[o] = h;
        } else if (tid >= 608 && tid < 630) {
            if (t > 0) {
                int o = tid - 608;
                float v = sig(dot4<0, 24>(wA, (const float4*)sHR, b_main));
                size_t oi = ((size_t)b * TT + (t - 1)) * 22 + o;
                if (F32) odf[oi] = v; else odh[oi] = __float2bfloat16(v);
            }
        }
        __syncthreads();

        // ---- S3: noise ih [waves 5-7] || noise hh [waves 7-9] || vad_out(t) ----
        if (tid >= 320 && tid < 464) {
            sNPI[tid - 320] = dot4<0, 23>(wB, (const float4*)sNIN, b_aux);
        } else if (tid >= 464 && tid < 608) {
            sNPH[tid - 464] = dot4<0, 12>(wB, (const float4*)sHN, b_aux);
        } else if (tid == 312) {
            float v = sig(dot4<0, 6>(wA, (const float4*)sHV, b_main));
            size_t oi = (size_t)b * TT + t;
            if (F32) ovf[oi] = v; else ovh[oi] = __float2bfloat16(v);
        }
        __syncthreads();

        // ---- S4: noise update [wave 0] ----
        if (tid < 48) {
            float r = sig(sNPI[tid] + sNPH[tid]);
            float z = sig(sNPI[48 + tid] + sNPH[48 + tid]);
            float n = tanh_fast(sNPI[96 + tid] + r * sNPH[96 + tid]);
            float h = (1.f - z) * n + z * sHN[tid];
            sHN[tid] = h;
            sDIN[24 + tid] = fmaxf(h, 0.f);
        }
        __syncthreads();

        // ---- S5: den ih [waves 0-4] || x(t+1) -> sXT,sNIN [wave 7] ----
        if (tid < 288) {
            sGI[tid] = dot4<0, 29>(wA, (const float4*)sDIN, b_main);
        } else if (tid >= 464 && tid < 464 + FF) {
            int j = tid - 464;
            sXT[j] = xreg; sNIN[48 + j] = xreg;
            int t2 = (t + 2 < TT) ? (t + 2) : (TT - 1);
            xreg = F32 ? xbf[t2 * FF + j] : bf2f(xbh[t2 * FF + j]);
        }
        __syncthreads();

        // ---- S6: den update [waves 0-1] || dense(t+1) [w1/w2] || x->sDIN [wave 2] ----
        if (tid < 96) {
            float r = sig(sGI[tid] + sGH[tid]);
            float z = sig(sGI[96 + tid] + sGH[96 + tid]);
            float n = tanh_fast(sGI[192 + tid] + r * sGH[192 + tid]);
            float h = (1.f - z) * n + z * sHD[tid];
            sHD[tid] = h;
            sHR[tid] = fmaxf(h, 0.f);
        } else if (tid < 120) {
            int o = tid - 96;
            float v = tanh_fast(dot4<0, 11>(wB, (const float4*)sXT, b_aux));
            sTMP[o] = v; sNIN[o] = v;
        } else if (tid >= 128 && tid < 128 + FF) {
            int j = tid - 128;
            sDIN[72 + j] = sXT[j];
        }
        __syncthreads();
    }

    // ---- epilogue: out head for t = TT-1 ----
    if (tid >= 608 && tid < 630) {
        int o = tid - 608;
        float v = sig(dot4<0, 24>(wA, (const float4*)sHR, b_main));
        size_t oi = ((size_t)b * TT + (TT - 1)) * 22 + o;
        if (F32) odf[oi] = v; else odh[oi] = __float2bfloat16(v);
    }
}

extern "C" void kernel_launch(void* const* d_in, const int* in_sizes, int n_in,
                              void* d_out, int out_size, void* d_ws, size_t ws_size,
                              hipStream_t stream) {
    hipLaunchKernelGGL(rnn_fused, dim3(BB), dim3(NTHREADS), 0, stream,
                       d_in[0], d_in[1], d_in[2],
                       d_in[3], d_in[4], d_in[5], d_in[6],
                       d_in[7], d_in[8],
                       d_in[9], d_in[10], d_in[11], d_in[12],
                       d_in[13], d_in[14], d_in[15], d_in[16],
                       d_in[17], d_in[18], d_out);
}

// Round 5
// 22643.652 us; speedup vs baseline: 3.6921x; 3.6921x over previous
//
#include <hip/hip_runtime.h>
#include <hip/hip_bf16.h>

#define BB 256
#define TT 2000
#define FF 42
#define NTHREADS 640

__device__ __forceinline__ float bf2f(__hip_bfloat16 v) { return __bfloat162float(v); }
__device__ __forceinline__ float sig(float x) { return 1.0f / (1.0f + __expf(-x)); }
__device__ __forceinline__ float tanh_fast(float x) {
    float e = __expf(2.0f * x);
    return 1.0f - 2.0f / (e + 1.0f);
}
__device__ __forceinline__ float unpk_lo(unsigned u) {
    union { unsigned u; float f; } c; c.u = u << 16; return c.f;
}
__device__ __forceinline__ float unpk_hi(unsigned u) {
    union { unsigned u; float f; } c; c.u = u & 0xffff0000u; return c.f;
}
// fp32 -> bf16 bits, round-to-nearest-even
__device__ __forceinline__ unsigned f2bfbits(float f) {
    union { float f; unsigned u; } c; c.f = f;
    unsigned r = c.u + 0x7FFFu + ((c.u >> 16) & 1u);
    return r >> 16;
}
__device__ __forceinline__ unsigned pack2(float a, float b) {
    return f2bfbits(a) | (f2bfbits(b) << 16);
}
__device__ __forceinline__ float gld(const void* p, int i, bool f32) {
    return f32 ? ((const float*)p)[i] : bf2f(((const __hip_bfloat16*)p)[i]);
}

// LDS weight row (uint4 = 8 packed bf16 per read) · fp32 input (LDS float4
// broadcast), 4 acc chains. Row base must be 16B-aligned (stride = 4*odd dw).
template<int NQ>
__device__ __forceinline__ float dotL(const unsigned* __restrict__ wrow,
                                      const float4* __restrict__ in, float acc) {
    const uint4* w4 = (const uint4*)wrow;
    float a0 = acc, a1 = 0.f, a2 = 0.f, a3 = 0.f;
    #pragma unroll
    for (int q = 0; q < NQ; ++q) {
        uint4 u = w4[q];
        float4 d0 = in[2 * q], d1 = in[2 * q + 1];
        a0 = fmaf(unpk_lo(u.x), d0.x, a0);
        a1 = fmaf(unpk_hi(u.x), d0.y, a1);
        a2 = fmaf(unpk_lo(u.y), d0.z, a2);
        a3 = fmaf(unpk_hi(u.y), d0.w, a3);
        a0 = fmaf(unpk_lo(u.z), d1.x, a0);
        a1 = fmaf(unpk_hi(u.z), d1.y, a1);
        a2 = fmaf(unpk_lo(u.w), d1.z, a2);
        a3 = fmaf(unpk_hi(u.w), d1.w, a3);
    }
    return (a0 + a1) + (a2 + a3);
}

// Register-array weights (the ONE proven-promotable 57-dword array; rounds
// 1-4 showed >57 dwords of per-thread alloca => scratch => 47-59 GB HBM).
template<int NF4>
__device__ __forceinline__ float dot4r(const unsigned (&w)[57],
                                       const float4* __restrict__ in, float acc) {
    float a0 = acc, a1 = 0.f, a2 = 0.f, a3 = 0.f;
    #pragma unroll
    for (int i = 0; i < NF4; ++i) {
        float4 d = in[i];
        unsigned u0 = w[2 * i], u1 = w[2 * i + 1];
        a0 = fmaf(unpk_lo(u0), d.x, a0);
        a1 = fmaf(unpk_hi(u0), d.y, a1);
        a2 = fmaf(unpk_lo(u1), d.z, a2);
        a3 = fmaf(unpk_hi(u1), d.w, a3);
    }
    return (a0 + a1) + (a2 + a3);
}

// W[O][K] row-major -> dst[o*S + kp] packed bf16 pairs (Kw = K/2 dwords used,
// S = row stride in dwords, multiple of 4; pads pre-zeroed by caller)
__device__ void load_rows(unsigned* dst, const void* src, int O, int Kw, int K, int S,
                          int tid, int nt, bool f32) {
    for (int i = tid; i < O * Kw; i += nt) {
        int o = i / Kw, kp = i - o * Kw;
        dst[o * S + kp] = pack2(gld(src, o * K + 2 * kp, f32),
                                gld(src, o * K + 2 * kp + 1, f32));
    }
}

__global__ __launch_bounds__(NTHREADS, 1)
void rnn_fused(const void* __restrict__ x,
               const void* __restrict__ dense_w, const void* __restrict__ dense_b,
               const void* __restrict__ vad_w_ih, const void* __restrict__ vad_w_hh,
               const void* __restrict__ vad_b_ih, const void* __restrict__ vad_b_hh,
               const void* __restrict__ vad_out_w, const void* __restrict__ vad_out_b,
               const void* __restrict__ noise_w_ih, const void* __restrict__ noise_w_hh,
               const void* __restrict__ noise_b_ih, const void* __restrict__ noise_b_hh,
               const void* __restrict__ den_w_ih, const void* __restrict__ den_w_hh,
               const void* __restrict__ den_b_ih, const void* __restrict__ den_b_hh,
               const void* __restrict__ out_w, const void* __restrict__ out_b,
               void* __restrict__ d_out) {
    // ---- LDS weights (packed bf16, uint4-readable strides 12/28/52 dw) ----
    __shared__ __align__(16) unsigned sDW[24 * 28];    // dense rows (21dw used)
    __shared__ __align__(16) unsigned sVIH[72 * 12];   // vad ih rows (12dw)
    __shared__ __align__(16) unsigned sVHH[72 * 12];   // vad hh rows (12dw)
    __shared__ __align__(16) unsigned sNIH[144 * 52];  // noise ih rows (45dw used)
    __shared__ __align__(16) unsigned sNHH[144 * 28];  // noise hh rows (24dw used)
    __shared__ __align__(16) unsigned sOW[22 * 52];    // out rows (48dw used)
    __shared__ __align__(16) unsigned sVOW[12];        // vad_out row
    // ---- LDS activations/state/partials (fp32) ----
    __shared__ __align__(16) float sXT[48];    // x(t) (+6 pad zeros)
    __shared__ __align__(16) float sTMP[24];   // dense out
    __shared__ __align__(16) float sHV[24];    // h_vad
    __shared__ __align__(16) float sHN[48];    // h_noise
    __shared__ __align__(16) float sHD[96];    // h_den
    __shared__ __align__(16) float sHR[96];    // relu(h_den)
    __shared__ __align__(16) float sNIN[96];   // [tmp | vad | x] (+6 pad)
    __shared__ __align__(16) float sDIN[116];  // [vad | relu(noise) | x] (+2 pad)
    __shared__ float sNPI[144], sNPH[144];     // noise partials
    __shared__ float sGI[288], sGH[288];       // den partials
    __shared__ int sBad;

    const int tid = threadIdx.x;
    const int b = blockIdx.x;
    const int nt = NTHREADS;

    // ---- zero weight LDS (pads must be 0), init sBad ----
    if (tid == 0) sBad = 0;
    for (int i = tid; i < 24 * 28; i += nt) sDW[i] = 0u;
    for (int i = tid; i < 72 * 12; i += nt) { sVIH[i] = 0u; sVHH[i] = 0u; }
    for (int i = tid; i < 144 * 52; i += nt) sNIH[i] = 0u;
    for (int i = tid; i < 144 * 28; i += nt) sNHH[i] = 0u;
    for (int i = tid; i < 22 * 52; i += nt) sOW[i] = 0u;
    if (tid < 12) sVOW[tid] = 0u;
    __syncthreads();

    // ---- dtype detection (validated rounds 0-4) ----
    {
        const unsigned* w = (const unsigned*)dense_w;
        for (int i = tid; i < 500; i += nt) {
            float av = fabsf(unpk_lo(w[i]));
            if (!(av <= 1e3f)) { atomicAdd(&sBad, 1); break; }
        }
    }
    __syncthreads();
    const bool F32 = (sBad > 0);

    const float* xbf = (const float*)x + (size_t)b * TT * FF;
    const __hip_bfloat16* xbh = (const __hip_bfloat16*)x + (size_t)b * TT * FF;
    float* odf = (float*)d_out;
    __hip_bfloat16* odh = (__hip_bfloat16*)d_out;
    float* ovf = odf + (size_t)BB * TT * 22;
    __hip_bfloat16* ovh = odh + (size_t)BB * TT * 22;

    // ---- fill LDS weights ----
    load_rows(sDW,  dense_w,    24, 21, 42, 28, tid, nt, F32);
    load_rows(sVIH, vad_w_ih,   72, 12, 24, 12, tid, nt, F32);
    load_rows(sVHH, vad_w_hh,   72, 12, 24, 12, tid, nt, F32);
    load_rows(sNIH, noise_w_ih, 144, 45, 90, 52, tid, nt, F32);
    load_rows(sNHH, noise_w_hh, 144, 24, 48, 28, tid, nt, F32);
    load_rows(sOW,  out_w,      22, 48, 96, 52, tid, nt, F32);
    if (tid < 12) sVOW[tid] = pack2(gld(vad_out_w, 2 * tid, F32),
                                    gld(vad_out_w, 2 * tid + 1, F32));

    // ---- den weights in registers: EXACT round-0 form (proven promoted).
    //      ih rows on tid 0..287 (57 dw), hh rows on tid 320..607 (48 dw). ----
    unsigned wden[57];
    float bDen = 0.f;
    if (tid < 288) {
        #pragma unroll
        for (int i = 0; i < 57; ++i)
            wden[i] = pack2(gld(den_w_ih, tid * 114 + 2 * i, F32),
                            gld(den_w_ih, tid * 114 + 2 * i + 1, F32));
        bDen = gld(den_b_ih, tid, F32);
    } else if (tid >= 320 && tid < 608) {
        int o = tid - 320;
        #pragma unroll
        for (int i = 0; i < 48; ++i)
            wden[i] = pack2(gld(den_w_hh, o * 96 + 2 * i, F32),
                            gld(den_w_hh, o * 96 + 2 * i + 1, F32));
        #pragma unroll
        for (int i = 48; i < 57; ++i) wden[i] = 0u;
        bDen = gld(den_b_hh, o, F32);
    } else {
        #pragma unroll
        for (int i = 0; i < 57; ++i) wden[i] = 0u;
    }

    // ---- per-role bias scalars ----
    float bDn = 0.f, bNI = 0.f, bNH = 0.f, bOut = 0.f, bVo = 0.f;
    float bv0 = 0.f, bv1 = 0.f, bv2 = 0.f, bv3 = 0.f, bv4 = 0.f, bv5 = 0.f;
    float hvreg = 0.f;
    if (tid >= 96 && tid < 120) bDn = gld(dense_b, tid - 96, F32);
    if (tid >= 288 && tid < 312) {
        int o = tid - 288;
        bv0 = gld(vad_b_ih, o, F32);      bv1 = gld(vad_b_ih, 24 + o, F32);
        bv2 = gld(vad_b_ih, 48 + o, F32); bv3 = gld(vad_b_hh, o, F32);
        bv4 = gld(vad_b_hh, 24 + o, F32); bv5 = gld(vad_b_hh, 48 + o, F32);
    }
    if (tid == 312) bVo = gld(vad_out_b, 0, F32);
    if (tid >= 320 && tid < 464) bNI = gld(noise_b_ih, tid - 320, F32);
    if (tid >= 464 && tid < 608) bNH = gld(noise_b_hh, tid - 464, F32);
    if (tid >= 608 && tid < 630) bOut = gld(out_b, tid - 608, F32);

    // ---- prologue: zero state, stage x(0), prefetch x(1) ----
    for (int i = tid; i < 24; i += nt) { sHV[i] = 0.f; sTMP[i] = 0.f; }
    for (int i = tid; i < 48; i += nt) sHN[i] = 0.f;
    for (int i = tid; i < 96; i += nt) { sHD[i] = 0.f; sHR[i] = 0.f; }
    if (tid < 6) { sXT[42 + tid] = 0.f; sNIN[90 + tid] = 0.f; }
    if (tid < 2) sDIN[114 + tid] = 0.f;
    if (tid < FF) {
        float v = F32 ? xbf[tid] : bf2f(xbh[tid]);
        sXT[tid] = v; sNIN[48 + tid] = v; sDIN[72 + tid] = v;
    }
    float xreg = 0.f;
    if (tid >= 464 && tid < 464 + FF) {
        int j = tid - 464;
        xreg = F32 ? xbf[FF + j] : bf2f(xbh[FF + j]);
    }
    __syncthreads();
    // dense(0)
    if (tid >= 96 && tid < 120) {
        int o = tid - 96;
        float v = tanh_fast(dotL<6>(sDW + o * 28, (const float4*)sXT, bDn));
        sTMP[o] = v; sNIN[o] = v;
    }
    __syncthreads();

    for (int t = 0; t < TT; ++t) {
        // ---- S2: den hh [w5-9, regs] || vad fused GRU [w4, LDS] || out(t-1) [w9 hi] ----
        if (tid >= 320 && tid < 608) {
            sGH[tid - 320] = dot4r<24>(wden, (const float4*)sHD, bDen);
        } else if (tid >= 288 && tid < 312) {
            // all 24 vad threads in wave 4: lockstep read-then-write of sHV is safe
            int o = tid - 288;
            const float4* tmp4 = (const float4*)sTMP;
            const float4* hv4 = (const float4*)sHV;
            const unsigned* wi = sVIH + o * 12;
            const unsigned* wh = sVHH + o * 12;
            float xr = dotL<3>(wi,       tmp4, bv0);
            float xz = dotL<3>(wi + 288, tmp4, bv1);
            float xn = dotL<3>(wi + 576, tmp4, bv2);
            float hr = dotL<3>(wh,       hv4, bv3);
            float hz = dotL<3>(wh + 288, hv4, bv4);
            float hn = dotL<3>(wh + 576, hv4, bv5);
            float r = sig(xr + hr);
            float z = sig(xz + hz);
            float n = tanh_fast(xn + r * hn);
            float h = (1.f - z) * n + z * hvreg;
            hvreg = h;
            sHV[o] = h; sNIN[24 + o] = h; sDIN[o] = h;
        } else if (tid >= 608 && tid < 630) {
            if (t > 0) {
                int o = tid - 608;
                float v = sig(dotL<12>(sOW + o * 52, (const float4*)sHR, bOut));
                size_t oi = ((size_t)b * TT + (t - 1)) * 22 + o;
                if (F32) odf[oi] = v; else odh[oi] = __float2bfloat16(v);
            }
        }
        __syncthreads();

        // ---- S3: noise ih [w5-7] || noise hh [w7-9] || vad_out(t) ----
        if (tid >= 320 && tid < 464) {
            sNPI[tid - 320] = dotL<12>(sNIH + (tid - 320) * 52, (const float4*)sNIN, bNI);
        } else if (tid >= 464 && tid < 608) {
            sNPH[tid - 464] = dotL<6>(sNHH + (tid - 464) * 28, (const float4*)sHN, bNH);
        } else if (tid == 312) {
            float v = sig(dotL<3>(sVOW, (const float4*)sHV, bVo));
            size_t oi = (size_t)b * TT + t;
            if (F32) ovf[oi] = v; else ovh[oi] = __float2bfloat16(v);
        }
        __syncthreads();

        // ---- S4: noise update [wave 0] ----
        if (tid < 48) {
            float r = sig(sNPI[tid] + sNPH[tid]);
            float z = sig(sNPI[48 + tid] + sNPH[48 + tid]);
            float n = tanh_fast(sNPI[96 + tid] + r * sNPH[96 + tid]);
            float h = (1.f - z) * n + z * sHN[tid];
            sHN[tid] = h;
            sDIN[24 + tid] = fmaxf(h, 0.f);
        }
        __syncthreads();

        // ---- S5: den ih [w0-4, regs] || x(t+1) -> sXT,sNIN [w7] ----
        if (tid < 288) {
            float a = dot4r<28>(wden, (const float4*)sDIN, bDen);
            a = fmaf(unpk_lo(wden[56]), sDIN[112], a);
            a = fmaf(unpk_hi(wden[56]), sDIN[113], a);
            sGI[tid] = a;
        } else if (tid >= 464 && tid < 464 + FF) {
            int j = tid - 464;
            sXT[j] = xreg; sNIN[48 + j] = xreg;
            int t2 = (t + 2 < TT) ? (t + 2) : (TT - 1);
            xreg = F32 ? xbf[t2 * FF + j] : bf2f(xbh[t2 * FF + j]);
        }
        __syncthreads();

        // ---- S6: den update [w0-1] || dense(t+1) [w1/w2] || x->sDIN [w2] ----
        if (tid < 96) {
            float r = sig(sGI[tid] + sGH[tid]);
            float z = sig(sGI[96 + tid] + sGH[96 + tid]);
            float n = tanh_fast(sGI[192 + tid] + r * sGH[192 + tid]);
            float h = (1.f - z) * n + z * sHD[tid];
            sHD[tid] = h;
            sHR[tid] = fmaxf(h, 0.f);
        } else if (tid < 120) {
            int o = tid - 96;
            float v = tanh_fast(dotL<6>(sDW + o * 28, (const float4*)sXT, bDn));
            sTMP[o] = v; sNIN[o] = v;
        } else if (tid >= 128 && tid < 128 + FF) {
            int j = tid - 128;
            sDIN[72 + j] = sXT[j];
        }
        __syncthreads();
    }

    // ---- epilogue: out head for t = TT-1 ----
    if (tid >= 608 && tid < 630) {
        int o = tid - 608;
        float v = sig(dotL<12>(sOW + o * 52, (const float4*)sHR, bOut));
        size_t oi = ((size_t)b * TT + (TT - 1)) * 22 + o;
        if (F32) odf[oi] = v; else odh[oi] = __float2bfloat16(v);
    }
}

extern "C" void kernel_launch(void* const* d_in, const int* in_sizes, int n_in,
                              void* d_out, int out_size, void* d_ws, size_t ws_size,
                              hipStream_t stream) {
    hipLaunchKernelGGL(rnn_fused, dim3(BB), dim3(NTHREADS), 0, stream,
                       d_in[0], d_in[1], d_in[2],
                       d_in[3], d_in[4], d_in[5], d_in[6],
                       d_in[7], d_in[8],
                       d_in[9], d_in[10], d_in[11], d_in[12],
                       d_in[13], d_in[14], d_in[15], d_in[16],
                       d_in[17], d_in[18], d_out);
}